// Round 12
// baseline (8745.491 us; speedup 1.0000x reference)
//
#include <hip/hip_runtime.h>
#include <stdint.h>
#include <math.h>

#define NS 8192
#define NSTEPS 200
#define DBc 128

typedef unsigned int u32;
typedef unsigned short u16;

// ws float-offset layout (float slots), total ~29.5 MB
#define WS_KEYINIT 64      // u32[2]
#define WS_KFIN   66       // u32[2]
#define WS_KC     128      // u32[400]
#define WS_KST    640      // u32[6*199] -> ends 1834
#define WS_IDX    2048     // int[200]
#define WS_U1     2560     // float[200] precomputed systematic-resample uniforms
#define WS_U2     2816     // float[200] precomputed ref-draw uniforms
#define WS_LL     4096                    // [200][8192]
#define WS_H      (WS_LL+NSTEPS*NS)
#define WS_LLN    (WS_H+NSTEPS*NS)
#define WS_ANC_F  (WS_LLN+NSTEPS*NS)      // u16[199*8192]
#define WS_CKPT   (WS_ANC_F+(NSTEPS-1)*NS/2)  // [25][8192][8]

// ======================= threefry2x32-20 (validated r1-r10) =======================
__device__ __forceinline__ u32 rotl32(u32 v, int r){ return (v<<r)|(v>>(32-r)); }

__device__ __forceinline__ void tf2x32(u32 k0,u32 k1,u32 c0,u32 c1,u32&o0,u32&o1){
  u32 ks2 = k0^k1^0x1BD11BDAu;
  u32 x0=c0+k0, x1=c1+k1;
#define TFR(R) { x0+=x1; x1=rotl32(x1,(R)); x1^=x0; }
  TFR(13) TFR(15) TFR(26) TFR(6)
  x0+=k1;  x1+=ks2+1u;
  TFR(17) TFR(29) TFR(16) TFR(24)
  x0+=ks2; x1+=k0+2u;
  TFR(13) TFR(15) TFR(26) TFR(6)
  x0+=k0;  x1+=k1+3u;
  TFR(17) TFR(29) TFR(16) TFR(24)
  x0+=k1;  x1+=ks2+4u;
  TFR(13) TFR(15) TFR(26) TFR(6)
  x0+=ks2; x1+=k0+5u;
#undef TFR
  o0=x0; o1=x1;
}

__device__ __forceinline__ u32 jax_bits_elem(u32 k0,u32 k1,u32 i){
  u32 a,b; tf2x32(k0,k1,0u,i,a,b); return a^b;
}

__device__ __forceinline__ float bits_to_f01(u32 bits){
  return __uint_as_float((bits>>9)|0x3f800000u) - 1.0f;
}

__device__ __forceinline__ float log1pf_acc(float a){
#pragma clang fp contract(off)
  float u = 1.0f + a;
  if (u == 1.0f) return a;
  float l = logf(u);
  return l * (a / (u - 1.0f));
}

__device__ __forceinline__ float erfinv_xla(float x){
#pragma clang fp contract(off)
  float a = -(x*x);
  float w = -log1pf_acc(a);
  float p;
  if (w < 5.0f){
    w = w - 2.5f;
    p = 2.81022636e-08f;
    p = 3.43273939e-07f + p*w;
    p = -3.5233877e-06f + p*w;
    p = -4.39150654e-06f + p*w;
    p = 0.00021858087f  + p*w;
    p = -0.00125372503f + p*w;
    p = -0.00417768164f + p*w;
    p = 0.246640727f    + p*w;
    p = 1.50140941f     + p*w;
  } else {
    w = sqrtf(w) - 3.0f;
    p = -0.000200214257f;
    p = 0.000100950558f + p*w;
    p = 0.00134934322f  + p*w;
    p = -0.00367342844f + p*w;
    p = 0.00573950773f  + p*w;
    p = -0.0076224613f  + p*w;
    p = 0.00943887047f  + p*w;
    p = 1.00167406f     + p*w;
    p = 2.83297682f     + p*w;
  }
  return p*x;
}

__device__ __forceinline__ float jax_normal_elem(u32 k0,u32 k1,u32 i){
#pragma clang fp contract(off)
  float f = bits_to_f01(jax_bits_elem(k0,k1,i));
  float u = f*2.0f + (-0.99999994039535522f);
  u = fmaxf(-0.99999994039535522f, u);
  return 1.41421356237309515f * erfinv_xla(u);
}

__device__ __forceinline__ float jax_uniform01_scalar(u32 k0,u32 k1){
  return bits_to_f01(jax_bits_elem(k0,k1,0u));
}

// ======================= wave helpers =======================
__device__ __forceinline__ float wave_max(float v){
  #pragma unroll
  for(int m=1;m<64;m<<=1) v=fmaxf(v,__shfl_xor(v,m,64));
  return v;
}
__device__ __forceinline__ float wave_incl_scan(float v,int lane){
  #pragma unroll
  for(int o=1;o<64;o<<=1){ float u=__shfl_up(v,o,64); if(lane>=o) v+=u; }
  return v;
}

// r0-verbatim chol8 (runtime loops)
__device__ void chol8(const float* A,float* L){
  for(int c=0;c<8;c++){
    for(int r=c;r<8;r++){
      float s=A[r*8+c];
      for(int k=0;k<c;k++) s-=L[r*(r+1)/2+k]*L[c*(c+1)/2+k];
      L[r*(r+1)/2+c]=(r==c)? sqrtf(s) : s/L[c*(c+1)/2+c];
    }
  }
}

// h(Cm) = max{ i in [0,NS) : tau_i <= Cm }, or -1 if none. Pure-ALU binary
// search over i (tau_i computed in registers with the EXACT original
// expression); the compare tau<=Cm is the complement of the original
// searchsorted's Cm<tau on the same float bits -> exact inversion.
__device__ __forceinline__ int h_of(float Cm, float u1, float T1){
  int lo=0, hi=NS;
  while(lo<hi){
    int mid=(lo+hi)>>1;
    float pos=((float)mid+u1)*(1.0f/8192.0f);
    float tau=pos*T1;
    if(tau<=Cm) lo=mid+1; else hi=mid;
  }
  return lo-1;
}

// ======================= k_pre: key chain (+ precomputed uniforms) =======================
__global__ __launch_bounds__(256) void k_pre(const int* __restrict__ seedp, float* wsf){
  u32* KI=(u32*)(wsf+WS_KEYINIT); u32* KF=(u32*)(wsf+WS_KFIN);
  u32* KC=(u32*)(wsf+WS_KC); u32* KST=(u32*)(wsf+WS_KST);
  int tid=threadIdx.x;
  if(tid==0){
    u32 s=(u32)seedp[0];
    u32 a,b;
    tf2x32(0u,s,0u,0u,a,b); KC[0]=a; KC[1]=b;      // key_0 = split(key).child0
    tf2x32(0u,s,0u,1u,a,b); KI[0]=a; KI[1]=b;      // key_init = child1
    for(int t=1;t<NSTEPS;t++){
      tf2x32(KC[2*(t-1)],KC[2*(t-1)+1],0u,0u,a,b);
      KC[2*t]=a; KC[2*t+1]=b;
    }
    KF[0]=KC[2*(NSTEPS-1)]; KF[1]=KC[2*(NSTEPS-1)+1];
  }
  __syncthreads();
  int t=tid;
  if(t>=1 && t<NSTEPS){
    u32 k0=KC[2*(t-1)], k1=KC[2*(t-1)+1];
    u32 s0,s1; tf2x32(k0,k1,0u,1u,s0,s1);          // key_step
    u32 ka0,ka1; tf2x32(s0,s1,0u,1u,ka0,ka1);      // k_anc
    u32 t0,t1;  tf2x32(s0,s1,0u,0u,t0,t1);
    u32 kr0,kr1; tf2x32(t0,t1,0u,1u,kr0,kr1);      // k_ref
    u32 u0,u1;  tf2x32(t0,t1,0u,0u,u0,u1);
    u32 w0,w1;  tf2x32(u0,u1,0u,1u,w0,w1);         // k_state
    u32* p=KST+6*(t-1);
    p[0]=ka0;p[1]=ka1;p[2]=kr0;p[3]=kr1;p[4]=w0;p[5]=w1;
    // bitwise-identical values k_weights used to recompute per step (integer-exact hoist)
    wsf[WS_U1+t]=bits_to_f01(jax_bits_elem(ka0,ka1,0u));
    wsf[WS_U2+t]=bits_to_f01(jax_bits_elem(kr0,kr1,0u));
  }
}

// ======================= k_state v8: cooperative wave-split ====================
// FROZEN TEXT (round-9 passing artifact, 2433us, absmax 0.01953125) — do not
// edit: k_state recompiles re-roll fma-contraction choices and risk
// resampling-index flips (r7/r10 lessons; 3 wins / 4 losses on that coin).
// Block = 320 threads: wave 0 ("A") owns 64 particles and runs the r0/r6
// serial chain verbatim; waves 1-4 ("helpers", 256 lanes) compute the 64x128
// independent dot+cos values per step into s_b. b values are bitwise
// location-independent (same source expression, same cosf, st read as an
// exact LDS copy), so A's ax chain — exact r0 j-ascending order — gets
// bit-identical inputs. Per-step handshake: A publishes st -> barrier ->
// helpers fill s_b -> barrier -> A consumes. Both branches execute the same
// barrier sequence (199 x 2).
// s_b rows padded to 129 floats: A's lane p reads (129p+j) -> bank (p+j)%32,
// conflict-free; helper wave writes spread 2-way (free).
__global__ __launch_bounds__(320,1) void k_state(
    const float* __restrict__ obs, const float* __restrict__ inp,
    const float* __restrict__ mean, const float* __restrict__ icov,
    const float* __restrict__ coeff, const float* __restrict__ ecov,
    const float* __restrict__ refst, const float* __restrict__ Om,
    const float* __restrict__ ph, const float* __restrict__ Cm,
    float* wsf)
{
  __shared__ float s_Om[DBc*12];     // [j][k] row-major, 48B rows (float4-aligned)
  __shared__ float s_cfT[DBc*8];     // transposed: [j][d]
  __shared__ float s_ph[DBc];
  __shared__ float s_Cm[64];
  __shared__ float s_obs[NSTEPS*8];
  __shared__ float s_ref[NSTEPS*8];
  __shared__ float s_inp[NSTEPS*4];
  __shared__ u32   s_k[(NSTEPS-1)*2];
  __shared__ float s_st[64*9];       // per-particle state, padded stride 9
  __shared__ float s_b[64*129];      // cos values [p][j], padded stride 129

  const int tid=threadIdx.x;
  for(int x=tid;x<DBc*12;x+=320) s_Om[x]=Om[x];
  for(int x=tid;x<DBc*8;x+=320){ int j=x>>3,d=x&7; s_cfT[x]=coeff[d*DBc+j]; }
  for(int x=tid;x<DBc;x+=320) s_ph[x]=ph[x];
  for(int x=tid;x<64;x+=320) s_Cm[x]=Cm[x];
  for(int x=tid;x<NSTEPS*8;x+=320) s_obs[x]=obs[x];
  for(int x=tid;x<NSTEPS*8;x+=320) s_ref[x]=refst[x];
  for(int x=tid;x<NSTEPS*4;x+=320) s_inp[x]=inp[x];
  { const u32* KST=(const u32*)(wsf+WS_KST);
    for(int x=tid;x<(NSTEPS-1)*2;x+=320){ int tt=x>>1; s_k[x]=KST[6*tt+4+(x&1)]; } }
  __syncthreads();

  const float4* s_Om4=(const float4*)s_Om;
  const float4* s_cf4=(const float4*)s_cfT;

  if(tid<64){
    // ==================== particle wave (r6 text; b from s_b) ====================
    const int i=blockIdx.x*64+tid;
    const u32* KI=(const u32*)(wsf+WS_KEYINIT);
    float* LL=wsf+WS_LL; float* H=wsf+WS_H; float* LLN=wsf+WS_LLN;
    float* CKPT=wsf+WS_CKPT;

    float LEp[36];
    float L0p[36];
    chol8(icov,L0p); chol8(ecov,LEp);
    float st[8];
    if(i==NS-1){ for(int d=0;d<8;d++) st[d]=s_ref[d]; }
    else {
      float eps[8];
      #pragma unroll
      for(int d=0;d<8;d++) eps[d]=jax_normal_elem(KI[0],KI[1],(u32)(i*8+d));
      for(int d=0;d<8;d++){ float m=0.0f; for(int k=0;k<=d;k++) m+=eps[k]*L0p[d*(d+1)/2+k]; st[d]=mean[d]+m; }
    }
    { float* ck=CKPT+(size_t)i*8;     // checkpoint row 0 = state at t=0
      for(int d=0;d<8;d++) ck[d]=st[d]; }

    float c_ll=4.0f*logf((float)(2.0*M_PI*0.1*0.1));
    float hc1=0.0f; for(int d=0;d<8;d++) hc1+=logf(LEp[d*(d+1)/2+d]);
    float hc2=4.0f*logf((float)(2.0*M_PI));
    const float SSQ=(float)(0.1*0.1);

    for(int t=1;t<NSTEPS;t++){
      // publish st for the helper waves
      #pragma unroll
      for(int d=0;d<8;d++) s_st[tid*9+d]=st[d];
      __syncthreads();                 // B1: helpers may read st
      __syncthreads();                 // B2: s_b ready

      // --- A: exact r0 per-d chain, j ascending, b from LDS (bit-identical) ---
      float ax[8]={0,0,0,0,0,0,0,0};
      for(int j=0;j<DBc;j++){
        float b=s_b[tid*129+j];
        float4 c0=s_cf4[j*2+0],c1=s_cf4[j*2+1];
        ax[0]+=b*c0.x; ax[1]+=b*c0.y; ax[2]+=b*c0.z; ax[3]+=b*c0.w;
        ax[4]+=b*c1.x; ax[5]+=b*c1.y; ax[6]+=b*c1.z; ax[7]+=b*c1.w;
      }
      float S=0.0f;
      for(int d=0;d<8;d++){
        float m=0.0f;
        #pragma unroll
        for(int k=0;k<8;k++) m+=ax[k]*s_Cm[d*8+k];
        float r=s_obs[t*8+d]-m; S+=r*r;
      }
      float ll=(-0.5f*S)/SSQ - c_ll;
      float sol[8]; float q=0.0f;
      for(int d=0;d<8;d++){
        float s=s_ref[t*8+d]-ax[d];
        for(int k=0;k<d;k++) s-=LEp[d*(d+1)/2+k]*sol[k];
        sol[d]=s/LEp[d*(d+1)/2+d];
        q+=sol[d]*sol[d];
      }
      float h=(-0.5f*q - hc1) - hc2;
      LL[(size_t)t*NS+i]=ll;
      H[(size_t)t*NS+i]=h;

      // --- P: exact (r0 order; 8 independent RNG chains) ---
      if(i==NS-1){ for(int d=0;d<8;d++) st[d]=s_ref[t*8+d]; }
      else {
        const u32 kp4=s_k[2*(t-1)], kp5=s_k[2*(t-1)+1];
        float eps[8];
        #pragma unroll
        for(int d=0;d<8;d++) eps[d]=jax_normal_elem(kp4,kp5,(u32)(i*8+d));
        for(int d=0;d<8;d++){ float m=0.0f; for(int k=0;k<=d;k++) m+=eps[k]*LEp[d*(d+1)/2+k]; st[d]=ax[d]+m; }
      }
      float S2n=0.0f;
      for(int d=0;d<8;d++){
        float m=0.0f;
        #pragma unroll
        for(int k=0;k<8;k++) m+=st[k]*s_Cm[d*8+k];
        float r=s_obs[t*8+d]-m; S2n+=r*r;
      }
      float lln=(-0.5f*S2n)/SSQ - c_ll;
      LLN[(size_t)t*NS+i]=lln;

      if((t&7)==0){
        float* ck=CKPT+((size_t)(t>>3)*NS+i)*8;
        for(int d=0;d<8;d++) ck[d]=st[d];
      }
    }
  } else {
    // ==================== helper waves: dot+cos producers ====================
    const int l=tid-64;          // 0..255
    const int p=l&63;            // particle within block
    const int jg=l>>6;           // j-group 0..3 (32 j's each)
    for(int t=1;t<NSTEPS;t++){
      __syncthreads();                 // B1: st published
      float z[12];
      #pragma unroll
      for(int d=0;d<8;d++) z[d]=s_st[p*9+d];
      z[8]=s_inp[t*4+0]; z[9]=s_inp[t*4+1]; z[10]=s_inp[t*4+2]; z[11]=s_inp[t*4+3];
      for(int jj=0;jj<32;jj++){
        const int j=jg*32+jj;
        float4 o0=s_Om4[j*3+0],o1=s_Om4[j*3+1],o2=s_Om4[j*3+2];
        float dot=0.0f;
        dot+=z[0]*o0.x; dot+=z[1]*o0.y; dot+=z[2]*o0.z; dot+=z[3]*o0.w;
        dot+=z[4]*o1.x; dot+=z[5]*o1.y; dot+=z[6]*o1.z; dot+=z[7]*o1.w;
        dot+=z[8]*o2.x; dot+=z[9]*o2.y; dot+=z[10]*o2.z; dot+=z[11]*o2.w;
        float dd=dot+s_ph[j];
        s_b[p*129+j]=cosf(dd);
      }
      __syncthreads();                 // B2: s_b ready
    }
  }
}

// ======================= k_weights: inverse-scatter resampling (no probe chains) ====
// Drift-safe lane (contraction-free FP; 3/3 k_weights edits preserved k_state
// bits). Changes vs the r9-passing text (swz reverted — r11 showed it costs):
// the per-item gallop searches (chained ~120cy LDS probes) are replaced by the
// EXACT inverse: for each owned CUM entry m, h(m)=max{i: tau_i<=CUM[m]} is
// found by a pure-ALU binary search over i (tau_i computed in registers with
// the original expression); items (h(m-1),h(m)] are assigned m via an LDS
// scatter SLO[i]=m. Boundary h(base-1) is recomputed from the stored
// CUM[base-1] — the same bits the neighbor used — so ranges partition
// [0,NS-1] exactly. Same compares on same bits -> ANC/IDX identical by
// construction. Clamp lo>NS-1 == forcing the last m's range end to NS-1.
__global__ __launch_bounds__(1024) void k_weights(float* wsf){
  const int tid=threadIdx.x;
  const int lane=tid&63;
  const int wid=tid>>6;       // 0..15
  const int base=tid*8;
  const u32* KF=(const u32*)(wsf+WS_KFIN);
  const float* LL=wsf+WS_LL;
  const float* H=wsf+WS_H;
  const float* LLN=wsf+WS_LLN;
  u16* ANC=(u16*)(wsf+WS_ANC_F);
  int* IDX=(int*)(wsf+WS_IDX);

  __shared__ float CUM[NS];                 // 32 KB
  __shared__ float CUM2[NS];                // 32 KB
  __shared__ float LLS[NS];                 // 32 KB — LL row t (exact copy)
  __shared__ u16   SLO[NS];                 // 16 KB — per-item ancestor index
  __shared__ float WMX[16],WMX2[16],WSM[16],WSM2[16];
  __shared__ float s_U1[NSTEPS], s_U2[NSTEPS];

  for(int x=tid;x<NSTEPS;x+=1024){ s_U1[x]=wsf[WS_U1+x]; s_U2[x]=wsf[WS_U2+x]; }

  float lw[8];
  #pragma unroll
  for(int k=0;k<8;k++) lw[k]=0.0f;

  // prefetch rows for t=1
  float r_ll[8],r_h[8],r_lln[8];
  {
    const float* LLt=LL+(size_t)1*NS;
    const float* Ht=H+(size_t)1*NS;
    const float* LLNt=LLN+(size_t)1*NS;
    #pragma unroll
    for(int k=0;k<8;k++){ r_ll[k]=LLt[base+k]; r_h[k]=Ht[base+k]; r_lln[k]=LLNt[base+k]; }
  }

  for(int t=1;t<NSTEPS;t++){
    float s1v[8],s2v[8];
    float m1=-INFINITY,m2=-INFINITY;
    #pragma unroll
    for(int k=0;k<8;k++){
      float llv=r_ll[k], hv=r_h[k];
      s1v[k]=llv+lw[k];
      s2v[k]=s1v[k]+hv;
      m1=fmaxf(m1,s1v[k]); m2=fmaxf(m2,s2v[k]);
    }
    float wm1=wave_max(m1), wm2=wave_max(m2);
    if(lane==0){ WMX[wid]=wm1; WMX2[wid]=wm2; }
    __syncthreads();                               // sync 1
    // stage LL row t (values already in registers; prev step's LLS reads are
    // ordered before this overwrite by sync 1)
    #pragma unroll
    for(int k=0;k<8;k++) LLS[base+k]=r_ll[k];
    float M1=WMX[0],M2=WMX2[0];
    #pragma unroll
    for(int w=1;w<16;w++){ M1=fmaxf(M1,WMX[w]); M2=fmaxf(M2,WMX2[w]); }

    float e1[8],e2[8]; float ts1=0.0f,ts2=0.0f;
    #pragma unroll
    for(int k=0;k<8;k++){
      e1[k]=expf(s1v[k]-M1); ts1+=e1[k];
      e2[k]=expf(s2v[k]-M2); ts2+=e2[k];
    }
    float is1=wave_incl_scan(ts1,lane);
    float is2=wave_incl_scan(ts2,lane);
    if(lane==63){ WSM[wid]=is1; WSM2[wid]=is2; }
    __syncthreads();                               // sync 2
    float T1=0.0f,T2=0.0f,woff1=0.0f,woff2=0.0f;
    #pragma unroll
    for(int w=0;w<16;w++){
      float a=WSM[w], b=WSM2[w];
      T1+=a; T2+=b;
      if(w<wid){ woff1+=a; woff2+=b; }
    }
    float excl1=woff1+(is1-ts1);
    float excl2=woff2+(is2-ts2);

    float runv[8];
    { float run=excl1;
      #pragma unroll
      for(int k=0;k<8;k++){ run+=e1[k]; CUM[base+k]=run; runv[k]=run; } }
    { float run=excl2;
      #pragma unroll
      for(int k=0;k<8;k++){ run+=e2[k]; CUM2[base+k]=run; } }
    __syncthreads();                               // sync 3

    // snapshot row t's lln, then issue the t+1 prefetch NOW so HBM latency
    // hides under the assignment phase
    float cur_lln[8];
    #pragma unroll
    for(int k=0;k<8;k++) cur_lln[k]=r_lln[k];
    if(t+1<NSTEPS){
      const float* LLt2=LL+(size_t)(t+1)*NS;
      const float* Ht2=H+(size_t)(t+1)*NS;
      const float* LLNt2=LLN+(size_t)(t+1)*NS;
      #pragma unroll
      for(int k=0;k<8;k++){ r_ll[k]=LLt2[base+k]; r_h[k]=Ht2[base+k]; r_lln[k]=LLNt2[base+k]; }
    }

    float u1=s_U1[t];
    // h for own 8 CUM values (register copies == stored bits) — pure ALU
    int hm[8];
    #pragma unroll
    for(int k=0;k<8;k++) hm[k]=h_of(runv[k],u1,T1);
    // boundary: h(base-1) from the stored value (same bits the neighbor used)
    int prevh;
    if(base==0) prevh=-1;
    else prevh=h_of(CUM[base-1],u1,T1);
    // scatter: items (h(m-1), h(m)] get ancestor m; last m absorbs the clamp
    #pragma unroll
    for(int k=0;k<8;k++){
      int m=base+k;
      int iHi=(m==NS-1)? (NS-1) : hm[k];
      for(int i=prevh+1;i<=iHi;i++) SLO[i]=(u16)m;
      prevh=hm[k];
    }
    // ref-particle draw (CUM2 ready since sync 3; one thread, hidden here)
    float lwn[8];
    if(tid==1023){
      float u2=s_U2[t];
      float tau=u2*T2;
      int lo=0,hi=NS;
      while(lo<hi){ int mid=(lo+hi)>>1; if(CUM2[mid]<tau) lo=mid+1; else hi=mid; }
      if(lo>NS-1) lo=NS-1;
      ANC[(size_t)(t-1)*NS+(NS-1)]=(u16)lo;
      lwn[7]=cur_lln[7]-LLS[lo];
    }
    __syncthreads();                               // sync 4: SLO complete

    #pragma unroll
    for(int k=0;k<8;k++){
      int i=base+k;
      if(i!=NS-1){
        int lo=(int)SLO[i];
        ANC[(size_t)(t-1)*NS+i]=(u16)lo;
        lwn[k]=cur_lln[k]-LLS[lo];
      }
    }
    #pragma unroll
    for(int k=0;k<8;k++) lw[k]=lwn[k];
    // no trailing sync: next iteration's sync 1 orders this step's CUM/LLS/SLO
    // reads before the next writes (which happen only after sync 1/2/3).
  }

  // ===== final softmax over lw, draw, backward chain (r0 verbatim) =====
  {
    float m=-INFINITY;
    #pragma unroll
    for(int k=0;k<8;k++) m=fmaxf(m,lw[k]);
    float wm=wave_max(m);
    if(lane==0) WMX[wid]=wm;
    __syncthreads();
    float M=WMX[0];
    #pragma unroll
    for(int w=1;w<16;w++) M=fmaxf(M,WMX[w]);
    float e[8]; float ts=0.0f;
    #pragma unroll
    for(int k=0;k<8;k++){ e[k]=expf(lw[k]-M); ts+=e[k]; }
    float is=wave_incl_scan(ts,lane);
    if(lane==63) WSM[wid]=is;
    __syncthreads();
    float T=0.0f,woff=0.0f;
    #pragma unroll
    for(int w=0;w<16;w++){ T+=WSM[w]; if(w<wid) woff+=WSM[w]; }
    float run=woff+(is-ts);
    #pragma unroll
    for(int k=0;k<8;k++){ run+=e[k]; CUM[base+k]=run; }
    __syncthreads();
    if(tid==0){
      float u=jax_uniform01_scalar(KF[0],KF[1]);
      float tau=u*T;
      int lo=0,hi=NS;
      while(lo<hi){ int mid=(lo+hi)>>1; if(CUM[mid]<tau) lo=mid+1; else hi=mid; }
      if(lo>NS-1) lo=NS-1;
      int b=lo;
      IDX[NSTEPS-1]=b;
      for(int r=NSTEPS-2;r>=0;r--){ b=(int)ANC[(size_t)r*NS+b]; IDX[r]=b; }
    }
  }
}

// ======================= k_replay: r8/r9 passing version (verbatim, FROZEN) ================
__global__ __launch_bounds__(256) void k_replay(
    const float* __restrict__ inp, const float* __restrict__ refst,
    const float* __restrict__ ecov, const float* __restrict__ Om,
    const float* __restrict__ ph, const float* __restrict__ coeff,
    const float* __restrict__ wsf, float* __restrict__ out)
{
  int task=blockIdx.x*blockDim.x+threadIdx.x;
  if(task>=NSTEPS) return;
  const int* IDX=(const int*)(wsf+WS_IDX);
  const u32* KST=(const u32*)(wsf+WS_KST);
  const float* CKPT=wsf+WS_CKPT;
  int t=task, p=IDX[t];
  if(p==NS-1){ for(int d=0;d<8;d++) out[t*8+d]=refst[t*8+d]; return; }
  float LEp[36]; chol8(ecov,LEp);
  int c=(t>>3)<<3;
  const float* ck=CKPT+((size_t)(t>>3)*NS+p)*8;
  float st[8];
  for(int d=0;d<8;d++) st[d]=ck[d];
  for(int s=c+1;s<=t;s++){
    float z[12];
    for(int d=0;d<8;d++) z[d]=st[d];
    for(int k=0;k<4;k++) z[8+k]=inp[s*4+k];
    float ax[8]={0,0,0,0,0,0,0,0};
    #pragma unroll 2
    for(int j=0;j<DBc;j++){
      float dot=0.0f;
      #pragma unroll
      for(int k=0;k<12;k++) dot+=z[k]*Om[j*12+k];
      float b=cosf(dot+ph[j]);
      #pragma unroll
      for(int d=0;d<8;d++) ax[d]+=b*coeff[d*DBc+j];
    }
    const u32* kp=KST+6*(s-1);
    float eps[8];
    #pragma unroll
    for(int d=0;d<8;d++) eps[d]=jax_normal_elem(kp[4],kp[5],(u32)(p*8+d));
    for(int d=0;d<8;d++){ float m=0.0f; for(int k=0;k<=d;k++) m+=eps[k]*LEp[d*(d+1)/2+k]; st[d]=ax[d]+m; }
  }
  for(int d=0;d<8;d++) out[t*8+d]=st[d];
}

// ======================= launch =======================
extern "C" void kernel_launch(void* const* d_in, const int* in_sizes, int n_in,
                              void* d_out, int out_size, void* d_ws, size_t ws_size,
                              hipStream_t stream) {
  const float* obs  =(const float*)d_in[0];
  const float* inp  =(const float*)d_in[1];
  const float* mean =(const float*)d_in[2];
  const float* icov =(const float*)d_in[3];
  const float* coeff=(const float*)d_in[4];
  const float* ecov =(const float*)d_in[5];
  const float* refst=(const float*)d_in[6];
  const float* Om   =(const float*)d_in[7];
  const float* ph   =(const float*)d_in[8];
  const float* Cm   =(const float*)d_in[9];
  const int*   seedp=(const int*)d_in[10];
  float* wsf=(float*)d_ws;
  float* out=(float*)d_out;

  hipLaunchKernelGGL(k_pre, dim3(1), dim3(256), 0, stream, seedp, wsf);
  hipLaunchKernelGGL(k_state, dim3(NS/64), dim3(320), 0, stream,
                     obs, inp, mean, icov, coeff, ecov, refst, Om, ph, Cm, wsf);
  hipLaunchKernelGGL(k_weights, dim3(1), dim3(1024), 0, stream, wsf);
  hipLaunchKernelGGL(k_replay, dim3(1), dim3(256), 0, stream,
                     inp, refst, ecov, Om, ph, coeff, wsf, out);
}

// Round 13
// 4427.048 us; speedup vs baseline: 1.9755x; 1.9755x over previous
//
#include <hip/hip_runtime.h>
#include <stdint.h>
#include <math.h>

#define NS 8192
#define NSTEPS 200
#define DBc 128

typedef unsigned int u32;
typedef unsigned short u16;

// ws float-offset layout (float slots), total ~29.5 MB
#define WS_KEYINIT 64      // u32[2]
#define WS_KFIN   66       // u32[2]
#define WS_KC     128      // u32[400]
#define WS_KST    640      // u32[6*199] -> ends 1834
#define WS_IDX    2048     // int[200]
#define WS_U1     2560     // float[200] precomputed systematic-resample uniforms
#define WS_U2     2816     // float[200] precomputed ref-draw uniforms
#define WS_LL     4096                    // [200][8192]
#define WS_H      (WS_LL+NSTEPS*NS)
#define WS_LLN    (WS_H+NSTEPS*NS)
#define WS_ANC_F  (WS_LLN+NSTEPS*NS)      // u16[199*8192]
#define WS_CKPT   (WS_ANC_F+(NSTEPS-1)*NS/2)  // [25][8192][8]

// ======================= threefry2x32-20 (validated r1-r10) =======================
__device__ __forceinline__ u32 rotl32(u32 v, int r){ return (v<<r)|(v>>(32-r)); }

__device__ __forceinline__ void tf2x32(u32 k0,u32 k1,u32 c0,u32 c1,u32&o0,u32&o1){
  u32 ks2 = k0^k1^0x1BD11BDAu;
  u32 x0=c0+k0, x1=c1+k1;
#define TFR(R) { x0+=x1; x1=rotl32(x1,(R)); x1^=x0; }
  TFR(13) TFR(15) TFR(26) TFR(6)
  x0+=k1;  x1+=ks2+1u;
  TFR(17) TFR(29) TFR(16) TFR(24)
  x0+=ks2; x1+=k0+2u;
  TFR(13) TFR(15) TFR(26) TFR(6)
  x0+=k0;  x1+=k1+3u;
  TFR(17) TFR(29) TFR(16) TFR(24)
  x0+=k1;  x1+=ks2+4u;
  TFR(13) TFR(15) TFR(26) TFR(6)
  x0+=ks2; x1+=k0+5u;
#undef TFR
  o0=x0; o1=x1;
}

__device__ __forceinline__ u32 jax_bits_elem(u32 k0,u32 k1,u32 i){
  u32 a,b; tf2x32(k0,k1,0u,i,a,b); return a^b;
}

__device__ __forceinline__ float bits_to_f01(u32 bits){
  return __uint_as_float((bits>>9)|0x3f800000u) - 1.0f;
}

__device__ __forceinline__ float log1pf_acc(float a){
#pragma clang fp contract(off)
  float u = 1.0f + a;
  if (u == 1.0f) return a;
  float l = logf(u);
  return l * (a / (u - 1.0f));
}

__device__ __forceinline__ float erfinv_xla(float x){
#pragma clang fp contract(off)
  float a = -(x*x);
  float w = -log1pf_acc(a);
  float p;
  if (w < 5.0f){
    w = w - 2.5f;
    p = 2.81022636e-08f;
    p = 3.43273939e-07f + p*w;
    p = -3.5233877e-06f + p*w;
    p = -4.39150654e-06f + p*w;
    p = 0.00021858087f  + p*w;
    p = -0.00125372503f + p*w;
    p = -0.00417768164f + p*w;
    p = 0.246640727f    + p*w;
    p = 1.50140941f     + p*w;
  } else {
    w = sqrtf(w) - 3.0f;
    p = -0.000200214257f;
    p = 0.000100950558f + p*w;
    p = 0.00134934322f  + p*w;
    p = -0.00367342844f + p*w;
    p = 0.00573950773f  + p*w;
    p = -0.0076224613f  + p*w;
    p = 0.00943887047f  + p*w;
    p = 1.00167406f     + p*w;
    p = 2.83297682f     + p*w;
  }
  return p*x;
}

__device__ __forceinline__ float jax_normal_elem(u32 k0,u32 k1,u32 i){
#pragma clang fp contract(off)
  float f = bits_to_f01(jax_bits_elem(k0,k1,i));
  float u = f*2.0f + (-0.99999994039535522f);
  u = fmaxf(-0.99999994039535522f, u);
  return 1.41421356237309515f * erfinv_xla(u);
}

__device__ __forceinline__ float jax_uniform01_scalar(u32 k0,u32 k1){
  return bits_to_f01(jax_bits_elem(k0,k1,0u));
}

// ======================= wave helpers =======================
__device__ __forceinline__ float wave_max(float v){
  #pragma unroll
  for(int m=1;m<64;m<<=1) v=fmaxf(v,__shfl_xor(v,m,64));
  return v;
}
__device__ __forceinline__ float wave_incl_scan(float v,int lane){
  #pragma unroll
  for(int o=1;o<64;o<<=1){ float u=__shfl_up(v,o,64); if(lane>=o) v+=u; }
  return v;
}

// r0-verbatim chol8 (runtime loops)
__device__ void chol8(const float* A,float* L){
  for(int c=0;c<8;c++){
    for(int r=c;r<8;r++){
      float s=A[r*8+c];
      for(int k=0;k<c;k++) s-=L[r*(r+1)/2+k]*L[c*(c+1)/2+k];
      L[r*(r+1)/2+c]=(r==c)? sqrtf(s) : s/L[c*(c+1)/2+c];
    }
  }
}

// fully-unrolled cholesky (static indices -> registers); used only by
// k_replay, whose outputs are tolerance-checked (not index-sensitive).
__device__ __forceinline__ void chol8u(const float* A,float* L){
  #pragma unroll
  for(int c=0;c<8;c++){
    #pragma unroll
    for(int r=0;r<8;r++){
      if(r>=c){
        float s=A[r*8+c];
        #pragma unroll
        for(int k=0;k<8;k++) if(k<c) s-=L[r*(r+1)/2+k]*L[c*(c+1)/2+k];
        L[r*(r+1)/2+c]=(r==c)? sqrtf(s) : s/L[c*(c+1)/2+c];
      }
    }
  }
}

// gallop searchsorted-left: first idx in [lo0,NS) with C[idx]>=tau.
// Identical FP compares on identical data as plain binary search -> identical result.
__device__ __forceinline__ int srch_from(const float* C,float tau,int lo0,int guess){
  int lo=lo0, hi=NS;
  int p=guess; if(p>NS-1)p=NS-1; if(p<lo0)p=lo0;
  if(C[p]>=tau){
    hi=p+1;
    int off=1;
    while(true){
      int q=p-off;
      if(q<lo0) break;                  // lo stays lo0
      if(C[q]>=tau){ hi=q+1; off<<=1; }
      else { lo=q+1; break; }
    }
  } else {
    lo=p+1;
    int off=1;
    while(true){
      int q=p+off;
      if(q>NS-1) break;                 // hi stays NS
      if(C[q]<tau){ lo=q+1; off<<=1; }
      else { hi=q+1; break; }
    }
  }
  while(lo<hi){ int mid=(lo+hi)>>1; if(C[mid]<tau) lo=mid+1; else hi=mid; }
  return lo;
}

// ======================= k_pre: key chain (+ precomputed uniforms) =======================
__global__ __launch_bounds__(256) void k_pre(const int* __restrict__ seedp, float* wsf){
  u32* KI=(u32*)(wsf+WS_KEYINIT); u32* KF=(u32*)(wsf+WS_KFIN);
  u32* KC=(u32*)(wsf+WS_KC); u32* KST=(u32*)(wsf+WS_KST);
  int tid=threadIdx.x;
  if(tid==0){
    u32 s=(u32)seedp[0];
    u32 a,b;
    tf2x32(0u,s,0u,0u,a,b); KC[0]=a; KC[1]=b;      // key_0 = split(key).child0
    tf2x32(0u,s,0u,1u,a,b); KI[0]=a; KI[1]=b;      // key_init = child1
    for(int t=1;t<NSTEPS;t++){
      tf2x32(KC[2*(t-1)],KC[2*(t-1)+1],0u,0u,a,b);
      KC[2*t]=a; KC[2*t+1]=b;
    }
    KF[0]=KC[2*(NSTEPS-1)]; KF[1]=KC[2*(NSTEPS-1)+1];
  }
  __syncthreads();
  int t=tid;
  if(t>=1 && t<NSTEPS){
    u32 k0=KC[2*(t-1)], k1=KC[2*(t-1)+1];
    u32 s0,s1; tf2x32(k0,k1,0u,1u,s0,s1);          // key_step
    u32 ka0,ka1; tf2x32(s0,s1,0u,1u,ka0,ka1);      // k_anc
    u32 t0,t1;  tf2x32(s0,s1,0u,0u,t0,t1);
    u32 kr0,kr1; tf2x32(t0,t1,0u,1u,kr0,kr1);      // k_ref
    u32 u0,u1;  tf2x32(t0,t1,0u,0u,u0,u1);
    u32 w0,w1;  tf2x32(u0,u1,0u,1u,w0,w1);         // k_state
    u32* p=KST+6*(t-1);
    p[0]=ka0;p[1]=ka1;p[2]=kr0;p[3]=kr1;p[4]=w0;p[5]=w1;
    // bitwise-identical values k_weights used to recompute per step (integer-exact hoist)
    wsf[WS_U1+t]=bits_to_f01(jax_bits_elem(ka0,ka1,0u));
    wsf[WS_U2+t]=bits_to_f01(jax_bits_elem(kr0,kr1,0u));
  }
}

// ======================= k_state v8: cooperative wave-split ====================
// FROZEN TEXT (round-9 passing artifact, 2433us, absmax 0.01953125) — do not
// edit: k_state recompiles re-roll fma-contraction choices and risk
// resampling-index flips (r7/r10 lessons; 3 wins / 4 losses on that coin).
// Block = 320 threads: wave 0 ("A") owns 64 particles and runs the r0/r6
// serial chain verbatim; waves 1-4 ("helpers", 256 lanes) compute the 64x128
// independent dot+cos values per step into s_b. b values are bitwise
// location-independent (same source expression, same cosf, st read as an
// exact LDS copy), so A's ax chain — exact r0 j-ascending order — gets
// bit-identical inputs. Per-step handshake: A publishes st -> barrier ->
// helpers fill s_b -> barrier -> A consumes. Both branches execute the same
// barrier sequence (199 x 2).
// s_b rows padded to 129 floats: A's lane p reads (129p+j) -> bank (p+j)%32,
// conflict-free; helper wave writes spread 2-way (free).
__global__ __launch_bounds__(320,1) void k_state(
    const float* __restrict__ obs, const float* __restrict__ inp,
    const float* __restrict__ mean, const float* __restrict__ icov,
    const float* __restrict__ coeff, const float* __restrict__ ecov,
    const float* __restrict__ refst, const float* __restrict__ Om,
    const float* __restrict__ ph, const float* __restrict__ Cm,
    float* wsf)
{
  __shared__ float s_Om[DBc*12];     // [j][k] row-major, 48B rows (float4-aligned)
  __shared__ float s_cfT[DBc*8];     // transposed: [j][d]
  __shared__ float s_ph[DBc];
  __shared__ float s_Cm[64];
  __shared__ float s_obs[NSTEPS*8];
  __shared__ float s_ref[NSTEPS*8];
  __shared__ float s_inp[NSTEPS*4];
  __shared__ u32   s_k[(NSTEPS-1)*2];
  __shared__ float s_st[64*9];       // per-particle state, padded stride 9
  __shared__ float s_b[64*129];      // cos values [p][j], padded stride 129

  const int tid=threadIdx.x;
  for(int x=tid;x<DBc*12;x+=320) s_Om[x]=Om[x];
  for(int x=tid;x<DBc*8;x+=320){ int j=x>>3,d=x&7; s_cfT[x]=coeff[d*DBc+j]; }
  for(int x=tid;x<DBc;x+=320) s_ph[x]=ph[x];
  for(int x=tid;x<64;x+=320) s_Cm[x]=Cm[x];
  for(int x=tid;x<NSTEPS*8;x+=320) s_obs[x]=obs[x];
  for(int x=tid;x<NSTEPS*8;x+=320) s_ref[x]=refst[x];
  for(int x=tid;x<NSTEPS*4;x+=320) s_inp[x]=inp[x];
  { const u32* KST=(const u32*)(wsf+WS_KST);
    for(int x=tid;x<(NSTEPS-1)*2;x+=320){ int tt=x>>1; s_k[x]=KST[6*tt+4+(x&1)]; } }
  __syncthreads();

  const float4* s_Om4=(const float4*)s_Om;
  const float4* s_cf4=(const float4*)s_cfT;

  if(tid<64){
    // ==================== particle wave (r6 text; b from s_b) ====================
    const int i=blockIdx.x*64+tid;
    const u32* KI=(const u32*)(wsf+WS_KEYINIT);
    float* LL=wsf+WS_LL; float* H=wsf+WS_H; float* LLN=wsf+WS_LLN;
    float* CKPT=wsf+WS_CKPT;

    float LEp[36];
    float L0p[36];
    chol8(icov,L0p); chol8(ecov,LEp);
    float st[8];
    if(i==NS-1){ for(int d=0;d<8;d++) st[d]=s_ref[d]; }
    else {
      float eps[8];
      #pragma unroll
      for(int d=0;d<8;d++) eps[d]=jax_normal_elem(KI[0],KI[1],(u32)(i*8+d));
      for(int d=0;d<8;d++){ float m=0.0f; for(int k=0;k<=d;k++) m+=eps[k]*L0p[d*(d+1)/2+k]; st[d]=mean[d]+m; }
    }
    { float* ck=CKPT+(size_t)i*8;     // checkpoint row 0 = state at t=0
      for(int d=0;d<8;d++) ck[d]=st[d]; }

    float c_ll=4.0f*logf((float)(2.0*M_PI*0.1*0.1));
    float hc1=0.0f; for(int d=0;d<8;d++) hc1+=logf(LEp[d*(d+1)/2+d]);
    float hc2=4.0f*logf((float)(2.0*M_PI));
    const float SSQ=(float)(0.1*0.1);

    for(int t=1;t<NSTEPS;t++){
      // publish st for the helper waves
      #pragma unroll
      for(int d=0;d<8;d++) s_st[tid*9+d]=st[d];
      __syncthreads();                 // B1: helpers may read st
      __syncthreads();                 // B2: s_b ready

      // --- A: exact r0 per-d chain, j ascending, b from LDS (bit-identical) ---
      float ax[8]={0,0,0,0,0,0,0,0};
      for(int j=0;j<DBc;j++){
        float b=s_b[tid*129+j];
        float4 c0=s_cf4[j*2+0],c1=s_cf4[j*2+1];
        ax[0]+=b*c0.x; ax[1]+=b*c0.y; ax[2]+=b*c0.z; ax[3]+=b*c0.w;
        ax[4]+=b*c1.x; ax[5]+=b*c1.y; ax[6]+=b*c1.z; ax[7]+=b*c1.w;
      }
      float S=0.0f;
      for(int d=0;d<8;d++){
        float m=0.0f;
        #pragma unroll
        for(int k=0;k<8;k++) m+=ax[k]*s_Cm[d*8+k];
        float r=s_obs[t*8+d]-m; S+=r*r;
      }
      float ll=(-0.5f*S)/SSQ - c_ll;
      float sol[8]; float q=0.0f;
      for(int d=0;d<8;d++){
        float s=s_ref[t*8+d]-ax[d];
        for(int k=0;k<d;k++) s-=LEp[d*(d+1)/2+k]*sol[k];
        sol[d]=s/LEp[d*(d+1)/2+d];
        q+=sol[d]*sol[d];
      }
      float h=(-0.5f*q - hc1) - hc2;
      LL[(size_t)t*NS+i]=ll;
      H[(size_t)t*NS+i]=h;

      // --- P: exact (r0 order; 8 independent RNG chains) ---
      if(i==NS-1){ for(int d=0;d<8;d++) st[d]=s_ref[t*8+d]; }
      else {
        const u32 kp4=s_k[2*(t-1)], kp5=s_k[2*(t-1)+1];
        float eps[8];
        #pragma unroll
        for(int d=0;d<8;d++) eps[d]=jax_normal_elem(kp4,kp5,(u32)(i*8+d));
        for(int d=0;d<8;d++){ float m=0.0f; for(int k=0;k<=d;k++) m+=eps[k]*LEp[d*(d+1)/2+k]; st[d]=ax[d]+m; }
      }
      float S2n=0.0f;
      for(int d=0;d<8;d++){
        float m=0.0f;
        #pragma unroll
        for(int k=0;k<8;k++) m+=st[k]*s_Cm[d*8+k];
        float r=s_obs[t*8+d]-m; S2n+=r*r;
      }
      float lln=(-0.5f*S2n)/SSQ - c_ll;
      LLN[(size_t)t*NS+i]=lln;

      if((t&7)==0){
        float* ck=CKPT+((size_t)(t>>3)*NS+i)*8;
        for(int d=0;d<8;d++) ck[d]=st[d];
      }
    }
  } else {
    // ==================== helper waves: dot+cos producers ====================
    const int l=tid-64;          // 0..255
    const int p=l&63;            // particle within block
    const int jg=l>>6;           // j-group 0..3 (32 j's each)
    for(int t=1;t<NSTEPS;t++){
      __syncthreads();                 // B1: st published
      float z[12];
      #pragma unroll
      for(int d=0;d<8;d++) z[d]=s_st[p*9+d];
      z[8]=s_inp[t*4+0]; z[9]=s_inp[t*4+1]; z[10]=s_inp[t*4+2]; z[11]=s_inp[t*4+3];
      for(int jj=0;jj<32;jj++){
        const int j=jg*32+jj;
        float4 o0=s_Om4[j*3+0],o1=s_Om4[j*3+1],o2=s_Om4[j*3+2];
        float dot=0.0f;
        dot+=z[0]*o0.x; dot+=z[1]*o0.y; dot+=z[2]*o0.z; dot+=z[3]*o0.w;
        dot+=z[4]*o1.x; dot+=z[5]*o1.y; dot+=z[6]*o1.z; dot+=z[7]*o1.w;
        dot+=z[8]*o2.x; dot+=z[9]*o2.y; dot+=z[10]*o2.z; dot+=z[11]*o2.w;
        float dd=dot+s_ph[j];
        s_b[p*129+j]=cosf(dd);
      }
      __syncthreads();                 // B2: s_b ready
    }
  }
}

// ======================= k_weights: r8 passing text RESTORED (verbatim, FROZEN) ====
// Both r11 (swz) and r12 (inverse-scatter) regressed; this structure is
// empirically near its floor. Do not touch further.
__global__ __launch_bounds__(1024) void k_weights(float* wsf){
  const int tid=threadIdx.x;
  const int lane=tid&63;
  const int wid=tid>>6;       // 0..15
  const int base=tid*8;
  const u32* KF=(const u32*)(wsf+WS_KFIN);
  const float* LL=wsf+WS_LL;
  const float* H=wsf+WS_H;
  const float* LLN=wsf+WS_LLN;
  u16* ANC=(u16*)(wsf+WS_ANC_F);
  int* IDX=(int*)(wsf+WS_IDX);

  __shared__ float CUM[NS];                 // 32 KB
  __shared__ float CUM2[NS];                // 32 KB
  __shared__ float LLS[NS];                 // 32 KB — LL row t (exact copy)
  __shared__ float WMX[16],WMX2[16],WSM[16],WSM2[16];
  __shared__ float s_U1[NSTEPS], s_U2[NSTEPS];

  for(int x=tid;x<NSTEPS;x+=1024){ s_U1[x]=wsf[WS_U1+x]; s_U2[x]=wsf[WS_U2+x]; }

  float lw[8];
  #pragma unroll
  for(int k=0;k<8;k++) lw[k]=0.0f;

  // prefetch rows for t=1
  float r_ll[8],r_h[8],r_lln[8];
  {
    const float* LLt=LL+(size_t)1*NS;
    const float* Ht=H+(size_t)1*NS;
    const float* LLNt=LLN+(size_t)1*NS;
    #pragma unroll
    for(int k=0;k<8;k++){ r_ll[k]=LLt[base+k]; r_h[k]=Ht[base+k]; r_lln[k]=LLNt[base+k]; }
  }

  for(int t=1;t<NSTEPS;t++){
    float s1v[8],s2v[8];
    float m1=-INFINITY,m2=-INFINITY;
    #pragma unroll
    for(int k=0;k<8;k++){
      float llv=r_ll[k], hv=r_h[k];
      s1v[k]=llv+lw[k];
      s2v[k]=s1v[k]+hv;
      m1=fmaxf(m1,s1v[k]); m2=fmaxf(m2,s2v[k]);
    }
    float wm1=wave_max(m1), wm2=wave_max(m2);
    if(lane==0){ WMX[wid]=wm1; WMX2[wid]=wm2; }
    __syncthreads();                               // sync 1
    // stage LL row t (values already in registers; prev step's LLS reads are
    // ordered before this overwrite by sync 1)
    #pragma unroll
    for(int k=0;k<8;k++) LLS[base+k]=r_ll[k];
    float M1=WMX[0],M2=WMX2[0];
    #pragma unroll
    for(int w=1;w<16;w++){ M1=fmaxf(M1,WMX[w]); M2=fmaxf(M2,WMX2[w]); }

    float e1[8],e2[8]; float ts1=0.0f,ts2=0.0f;
    #pragma unroll
    for(int k=0;k<8;k++){
      e1[k]=expf(s1v[k]-M1); ts1+=e1[k];
      e2[k]=expf(s2v[k]-M2); ts2+=e2[k];
    }
    float is1=wave_incl_scan(ts1,lane);
    float is2=wave_incl_scan(ts2,lane);
    if(lane==63){ WSM[wid]=is1; WSM2[wid]=is2; }
    __syncthreads();                               // sync 2
    float T1=0.0f,T2=0.0f,woff1=0.0f,woff2=0.0f;
    #pragma unroll
    for(int w=0;w<16;w++){
      float a=WSM[w], b=WSM2[w];
      T1+=a; T2+=b;
      if(w<wid){ woff1+=a; woff2+=b; }
    }
    float excl1=woff1+(is1-ts1);
    float excl2=woff2+(is2-ts2);

    { float run=excl1;
      #pragma unroll
      for(int k=0;k<8;k++){ run+=e1[k]; CUM[base+k]=run; } }
    { float run=excl2;
      #pragma unroll
      for(int k=0;k<8;k++){ run+=e2[k]; CUM2[base+k]=run; } }
    __syncthreads();                               // sync 3

    // snapshot row t's lln (still needed by the searches), then issue the
    // t+1 prefetch NOW so HBM latency hides under the search phase
    float cur_lln[8];
    #pragma unroll
    for(int k=0;k<8;k++) cur_lln[k]=r_lln[k];
    if(t+1<NSTEPS){
      const float* LLt2=LL+(size_t)(t+1)*NS;
      const float* Ht2=H+(size_t)(t+1)*NS;
      const float* LLNt2=LLN+(size_t)(t+1)*NS;
      #pragma unroll
      for(int k=0;k<8;k++){ r_ll[k]=LLt2[base+k]; r_h[k]=Ht2[base+k]; r_lln[k]=LLNt2[base+k]; }
    }

    float lwn[8];
    float u1=s_U1[t];
    int prev=0;
    #pragma unroll
    for(int k=0;k<8;k++){
      int i=base+k;
      if(i!=NS-1){
        float pos=((float)i+u1)*(1.0f/8192.0f);
        float tau=pos*T1;
        int lo=(k==0)? srch_from(CUM,tau,0,i)
                     : srch_from(CUM,tau,prev,prev);
        if(lo>NS-1) lo=NS-1;
        prev=lo;
        ANC[(size_t)(t-1)*NS+i]=(u16)lo;
        lwn[k]=cur_lln[k]-LLS[lo];
      }
    }
    if(tid==1023){
      float u2=s_U2[t];
      float tau=u2*T2;
      int lo=0,hi=NS;
      while(lo<hi){ int mid=(lo+hi)>>1; if(CUM2[mid]<tau) lo=mid+1; else hi=mid; }
      if(lo>NS-1) lo=NS-1;
      ANC[(size_t)(t-1)*NS+(NS-1)]=(u16)lo;
      lwn[7]=cur_lln[7]-LLS[lo];
    }
    #pragma unroll
    for(int k=0;k<8;k++) lw[k]=lwn[k];
    // no trailing sync: next iteration's sync 1 orders this step's CUM/LLS reads
    // before the next writes (which happen only after sync 1/2).
  }

  // ===== final softmax over lw, draw, backward chain (r0 verbatim) =====
  {
    float m=-INFINITY;
    #pragma unroll
    for(int k=0;k<8;k++) m=fmaxf(m,lw[k]);
    float wm=wave_max(m);
    if(lane==0) WMX[wid]=wm;
    __syncthreads();
    float M=WMX[0];
    #pragma unroll
    for(int w=1;w<16;w++) M=fmaxf(M,WMX[w]);
    float e[8]; float ts=0.0f;
    #pragma unroll
    for(int k=0;k<8;k++){ e[k]=expf(lw[k]-M); ts+=e[k]; }
    float is=wave_incl_scan(ts,lane);
    if(lane==63) WSM[wid]=is;
    __syncthreads();
    float T=0.0f,woff=0.0f;
    #pragma unroll
    for(int w=0;w<16;w++){ T+=WSM[w]; if(w<wid) woff+=WSM[w]; }
    float run=woff+(is-ts);
    #pragma unroll
    for(int k=0;k<8;k++){ run+=e[k]; CUM[base+k]=run; }
    __syncthreads();
    if(tid==0){
      float u=jax_uniform01_scalar(KF[0],KF[1]);
      float tau=u*T;
      int lo=0,hi=NS;
      while(lo<hi){ int mid=(lo+hi)>>1; if(CUM[mid]<tau) lo=mid+1; else hi=mid; }
      if(lo>NS-1) lo=NS-1;
      int b=lo;
      IDX[NSTEPS-1]=b;
      for(int r=NSTEPS-2;r>=0;r--){ b=(int)ANC[(size_t)r*NS+b]; IDX[r]=b; }
    }
  }
}

// ======================= k_replay v2: one block per task, wave-cooperative ====
// k_replay is NOT index-sensitive: it only recomputes states along the
// already-decided ancestral path and writes `out` (tolerance-checked, 0.043).
// So reassociation is safe here (unlike k_state/k_weights). 200 blocks x 64
// lanes; per step: 2 dot+cos per lane, butterfly tree-sum for ax (order-free,
// drift ~1e-6 over <=7 steps), one RNG normal per lane (bit-exact values),
// static-unrolled L*eps. Longest task ~7 steps, all tasks parallel.
__global__ __launch_bounds__(64) void k_replay(
    const float* __restrict__ inp, const float* __restrict__ refst,
    const float* __restrict__ ecov, const float* __restrict__ Om,
    const float* __restrict__ ph, const float* __restrict__ coeff,
    const float* __restrict__ wsf, float* __restrict__ out)
{
  const int t=blockIdx.x;
  const int lane=threadIdx.x;
  const int* IDX=(const int*)(wsf+WS_IDX);
  const u32* KST=(const u32*)(wsf+WS_KST);
  const float* CKPT=wsf+WS_CKPT;
  int p=IDX[t];
  if(p==NS-1){
    if(lane<8) out[t*8+lane]=refst[t*8+lane];
    return;
  }
  float LEp[36]; chol8u(ecov,LEp);
  int c=(t>>3)<<3;
  const float* ck=CKPT+((size_t)(t>>3)*NS+p)*8;
  float st[8];
  #pragma unroll
  for(int d=0;d<8;d++) st[d]=ck[d];
  for(int s=c+1;s<=t;s++){
    float z[12];
    #pragma unroll
    for(int d=0;d<8;d++) z[d]=st[d];
    #pragma unroll
    for(int k=0;k<4;k++) z[8+k]=inp[s*4+k];
    float ax[8];
    #pragma unroll
    for(int d=0;d<8;d++) ax[d]=0.0f;
    #pragma unroll
    for(int jj=0;jj<2;jj++){
      const int j=lane+jj*64;
      float dot=0.0f;
      #pragma unroll
      for(int k=0;k<12;k++) dot+=z[k]*Om[j*12+k];
      float b=cosf(dot+ph[j]);
      #pragma unroll
      for(int d=0;d<8;d++) ax[d]+=b*coeff[d*DBc+j];
    }
    // butterfly sum across 64 lanes (all lanes end with the full sum)
    #pragma unroll
    for(int m=1;m<64;m<<=1){
      #pragma unroll
      for(int d=0;d<8;d++) ax[d]+=__shfl_xor(ax[d],m,64);
    }
    const u32* kp=KST+6*(s-1);
    // one normal per lane (lane&7 = dim), broadcast via shfl — values bit-exact
    float eo=jax_normal_elem(kp[4],kp[5],(u32)(p*8+(lane&7)));
    float eps[8];
    #pragma unroll
    for(int d=0;d<8;d++) eps[d]=__shfl(eo,d,64);
    #pragma unroll
    for(int d=0;d<8;d++){
      float m=0.0f;
      #pragma unroll
      for(int k=0;k<8;k++) if(k<=d) m+=eps[k]*LEp[d*(d+1)/2+k];
      st[d]=ax[d]+m;
    }
  }
  if(lane<8) out[t*8+lane]=st[lane];
}

// ======================= launch =======================
extern "C" void kernel_launch(void* const* d_in, const int* in_sizes, int n_in,
                              void* d_out, int out_size, void* d_ws, size_t ws_size,
                              hipStream_t stream) {
  const float* obs  =(const float*)d_in[0];
  const float* inp  =(const float*)d_in[1];
  const float* mean =(const float*)d_in[2];
  const float* icov =(const float*)d_in[3];
  const float* coeff=(const float*)d_in[4];
  const float* ecov =(const float*)d_in[5];
  const float* refst=(const float*)d_in[6];
  const float* Om   =(const float*)d_in[7];
  const float* ph   =(const float*)d_in[8];
  const float* Cm   =(const float*)d_in[9];
  const int*   seedp=(const int*)d_in[10];
  float* wsf=(float*)d_ws;
  float* out=(float*)d_out;

  hipLaunchKernelGGL(k_pre, dim3(1), dim3(256), 0, stream, seedp, wsf);
  hipLaunchKernelGGL(k_state, dim3(NS/64), dim3(320), 0, stream,
                     obs, inp, mean, icov, coeff, ecov, refst, Om, ph, Cm, wsf);
  hipLaunchKernelGGL(k_weights, dim3(1), dim3(1024), 0, stream, wsf);
  hipLaunchKernelGGL(k_replay, dim3(NSTEPS), dim3(64), 0, stream,
                     inp, refst, ecov, Om, ph, coeff, wsf, out);
}